// Round 1
// baseline (2151.745 us; speedup 1.0000x reference)
//
#include <hip/hip_runtime.h>
#include <math.h>

// ---------------------------------------------------------------------------
// CogKR scoring pipeline, fp32 baseline with algebraic factorization:
//  (1) per-relation tables: relWr = rel@Wr, relWqr = rel@Wqr, relCand = rel@cand_W[128:256]
//  (2) nodeWs = node_hidden@Ws            (100000x256 GEMM)
//  (3) alpha_k: per-edge gather+relu+dot+sigmoid
//  (4) scatter_k: agg[tail_node] += [hr|te]*alpha   (fp32 atomics)
//  (5) h_prev = lrelu(gather(entity)@We2h + b)      (GEMM with row-gather)
//  (6) gx = agg@W_ih^T + b_ih ; gh = h_prev@W_hh^T + b_hh  (chunked x4, aliased ws)
//  (7) gru_ln_k: GRU elementwise + LayerNorm -> h_new
//  (8) hnewCand = h_new@cand_W[256:512] + cand_b
//  (9) score_k: per-edge te@cand_W[0:128] (block mini-GEMM) + gathers, lrelu,
//      dot rank_W[0:256], + qdot[batch] + rank_b
// Workspace budget ~311 MB (nodeWs region reused for gx/gh chunks).
// ---------------------------------------------------------------------------

#define ACT_NONE 0
#define ACT_LRELU 1

// ---------------- generic tiled fp32 GEMM: C = act(A@B + bias) ----------------
// A[M,K] row-major (optional row gather via a_idx), B[K,N] row-major, C[M,N].
// BM=BN=64, BK=16, 256 threads, 4x4 per thread. K%16==0, N%64==0 assumed.
__global__ __launch_bounds__(256) void gemm_k(
    const float* __restrict__ A, const float* __restrict__ B,
    const float* __restrict__ bias, float* __restrict__ C,
    int M, int N, int K, const int* __restrict__ a_idx, int act)
{
    __shared__ float As[16][68];
    __shared__ float Bs[16][68];
    const int tid = threadIdx.x;
    const int tx = tid & 15, ty = tid >> 4;
    const int m0 = blockIdx.x * 64, n0 = blockIdx.y * 64;

    float acc[4][4] = {};

    const int ar  = tid >> 2;          // 0..63 row-in-tile for A load
    const int ac4 = (tid & 3) * 4;     // k offset 0,4,8,12
    const int brow = tid >> 4;         // 0..15 k for B load
    const int bc4  = (tid & 15) * 4;   // 0..60 n offset

    const int gm = m0 + ar;
    const float* Arow = nullptr;
    if (gm < M) {
        int r = a_idx ? a_idx[gm] : gm;
        Arow = A + (size_t)r * K;
    }

    for (int k0 = 0; k0 < K; k0 += 16) {
        float4 av = make_float4(0.f, 0.f, 0.f, 0.f);
        if (Arow) av = *(const float4*)(Arow + k0 + ac4);
        As[ac4 + 0][ar] = av.x;
        As[ac4 + 1][ar] = av.y;
        As[ac4 + 2][ar] = av.z;
        As[ac4 + 3][ar] = av.w;
        float4 bv = *(const float4*)(B + (size_t)(k0 + brow) * N + n0 + bc4);
        *(float4*)&Bs[brow][bc4] = bv;
        __syncthreads();
        #pragma unroll
        for (int kk = 0; kk < 16; ++kk) {
            float4 a4 = *(float4*)&As[kk][ty << 2];
            float4 b4 = *(float4*)&Bs[kk][tx << 2];
            float avr[4] = {a4.x, a4.y, a4.z, a4.w};
            float bvr[4] = {b4.x, b4.y, b4.z, b4.w};
            #pragma unroll
            for (int i = 0; i < 4; ++i)
                #pragma unroll
                for (int j = 0; j < 4; ++j)
                    acc[i][j] = fmaf(avr[i], bvr[j], acc[i][j]);
        }
        __syncthreads();
    }

    const int n = n0 + (tx << 2);
    float4 bv4 = make_float4(0.f, 0.f, 0.f, 0.f);
    if (bias) bv4 = *(const float4*)(bias + n);
    #pragma unroll
    for (int i = 0; i < 4; ++i) {
        int m = m0 + (ty << 2) + i;
        if (m >= M) continue;
        float v0 = acc[i][0] + bv4.x;
        float v1 = acc[i][1] + bv4.y;
        float v2 = acc[i][2] + bv4.z;
        float v3 = acc[i][3] + bv4.w;
        if (act == ACT_LRELU) {
            v0 = v0 > 0.f ? v0 : 0.01f * v0;
            v1 = v1 > 0.f ? v1 : 0.01f * v1;
            v2 = v2 > 0.f ? v2 : 0.01f * v2;
            v3 = v3 > 0.f ? v3 : 0.01f * v3;
        }
        float4 out = make_float4(v0, v1, v2, v3);
        *(float4*)(C + (size_t)m * N + n) = out;
    }
}

// ---------------- transpose 768x256 -> 256x768 (for W_ih, W_hh) ----------------
__global__ __launch_bounds__(256) void transpose_k(
    const float* __restrict__ in, float* __restrict__ out)
{
    int t = blockIdx.x * 256 + threadIdx.x;   // t < 768*256
    int r = t >> 8, c = t & 255;
    out[(size_t)c * 768 + r] = in[t];
}

// ---------------- qdot[b] = query_repr[b] . rank_W[256:512] ----------------
__global__ __launch_bounds__(256) void qdot_k(
    const float* __restrict__ q, const float* __restrict__ rank_W,
    float* __restrict__ qdot)
{
    int b = blockIdx.x * 4 + (threadIdx.x >> 6);
    int l = threadIdx.x & 63;
    float s = 0.f;
    #pragma unroll
    for (int k = 0; k < 4; ++k) {
        int h = l + k * 64;
        s += q[(size_t)b * 256 + h] * rank_W[256 + h];
    }
    #pragma unroll
    for (int off = 32; off; off >>= 1) s += __shfl_xor(s, off, 64);
    if (l == 0) qdot[b] = s;
}

// ---------------- per-edge attention alpha ----------------
// alpha[e] = sigmoid( relu(nodeWs[hn] + relWr[er] + relWqr[qr] + bqr) . w_alpha + b_alpha )
// 32 edges/block; wave ty handles 8 edges; lane tx covers cols 4tx..4tx+3.
__global__ __launch_bounds__(256) void alpha_k(
    const float* __restrict__ nodeWs, const float* __restrict__ relWr,
    const float* __restrict__ relWqr, const float* __restrict__ bqr,
    const float* __restrict__ w_alpha, const float* __restrict__ b_alpha_p,
    const int* __restrict__ head_node, const int* __restrict__ edge_rel,
    const int* __restrict__ query_rel, float* __restrict__ alpha_out)
{
    const int tid = threadIdx.x;
    const int e0 = blockIdx.x * 32;
    __shared__ int hn[32], er[32], qr[32];
    if (tid < 32) {
        int e = e0 + tid;
        hn[tid] = head_node[e]; er[tid] = edge_rel[e]; qr[tid] = query_rel[e];
    }
    __syncthreads();
    const int tx = tid & 63, ty = tid >> 6;
    const int c = tx * 4;
    const float4 bq = *(const float4*)(bqr + c);
    const float4 wa = *(const float4*)(w_alpha + c);
    float part[8];
    #pragma unroll
    for (int i2 = 0; i2 < 8; ++i2) {
        int i = ty * 8 + i2;
        float4 a = *(const float4*)(nodeWs + (size_t)hn[i] * 256 + c);
        float4 b = *(const float4*)(relWr + (size_t)er[i] * 256 + c);
        float4 d = *(const float4*)(relWqr + (size_t)qr[i] * 256 + c);
        float x0 = fmaxf(a.x + b.x + d.x + bq.x, 0.f);
        float x1 = fmaxf(a.y + b.y + d.y + bq.y, 0.f);
        float x2 = fmaxf(a.z + b.z + d.z + bq.z, 0.f);
        float x3 = fmaxf(a.w + b.w + d.w + bq.w, 0.f);
        part[i2] = x0 * wa.x + x1 * wa.y + x2 * wa.z + x3 * wa.w;
    }
    #pragma unroll
    for (int off = 32; off; off >>= 1)
        #pragma unroll
        for (int i2 = 0; i2 < 8; ++i2)
            part[i2] += __shfl_xor(part[i2], off, 64);
    if (tx == 0) {
        float ba = b_alpha_p[0];
        #pragma unroll
        for (int i2 = 0; i2 < 8; ++i2)
            alpha_out[e0 + ty * 8 + i2] = 1.f / (1.f + __expf(-(part[i2] + ba)));
    }
}

// ---------------- segment-sum scatter: agg[tail_node] += [hr|te]*alpha ----------------
// 64 lanes per edge, float4 per lane (256 cols).
__global__ __launch_bounds__(256) void scatter_k(
    const float* __restrict__ relation_emb, const float* __restrict__ entity_emb,
    const float* __restrict__ alpha, const int* __restrict__ edge_rel,
    const int* __restrict__ tail_ent, const int* __restrict__ tail_node,
    float* __restrict__ agg)
{
    int gid = blockIdx.x * 256 + threadIdx.x;
    int e = gid >> 6, l = gid & 63;
    float a = alpha[e];
    int c = l * 4;
    const float* src = (c < 128)
        ? (relation_emb + (size_t)edge_rel[e] * 128 + c)
        : (entity_emb + (size_t)tail_ent[e] * 128 + (c - 128));
    float4 v = *(const float4*)src;
    float* dst = agg + (size_t)tail_node[e] * 256 + c;
    atomicAdd(dst + 0, v.x * a);
    atomicAdd(dst + 1, v.y * a);
    atomicAdd(dst + 2, v.z * a);
    atomicAdd(dst + 3, v.w * a);
}

// ---------------- GRU elementwise + LayerNorm ----------------
// One wave per node; gx/gh indexed by chunk-local node, h_prev/h_new by global.
__global__ __launch_bounds__(256) void gru_ln_k(
    const float* __restrict__ gx, const float* __restrict__ gh,
    const float* __restrict__ h_prev, const float* __restrict__ ln_g,
    const float* __restrict__ ln_b, float* __restrict__ h_new, int n0)
{
    int nl = blockIdx.x * 4 + (threadIdx.x >> 6);
    int lane = threadIdx.x & 63;
    int n = n0 + nl;
    const float* gxr = gx + (size_t)nl * 768;
    const float* ghr = gh + (size_t)nl * 768;
    const float* hpr = h_prev + (size_t)n * 256;
    float hv[4]; float s = 0.f, s2 = 0.f;
    #pragma unroll
    for (int q2 = 0; q2 < 4; ++q2) {
        int h = lane + q2 * 64;
        float xr = gxr[h], xz = gxr[256 + h], xn = gxr[512 + h];
        float hr_ = ghr[h], hz_ = ghr[256 + h], hn_ = ghr[512 + h];
        float hp = hpr[h];
        float r = 1.f / (1.f + __expf(-(xr + hr_)));
        float z = 1.f / (1.f + __expf(-(xz + hz_)));
        float nn = tanhf(xn + r * hn_);
        float v = (1.f - z) * nn + z * hp;
        hv[q2] = v; s += v; s2 += v * v;
    }
    #pragma unroll
    for (int off = 32; off; off >>= 1) {
        s  += __shfl_xor(s, off, 64);
        s2 += __shfl_xor(s2, off, 64);
    }
    float mean = s * (1.f / 256.f);
    float var  = s2 * (1.f / 256.f) - mean * mean;
    float rstd = rsqrtf(var + 1e-5f);
    float* outr = h_new + (size_t)n * 256;
    #pragma unroll
    for (int q2 = 0; q2 < 4; ++q2) {
        int h = lane + q2 * 64;
        outr[h] = (hv[q2] - mean) * rstd * ln_g[h] + ln_b[h];
    }
}

// ---------------- per-edge candidate + rank scoring ----------------
// 32 edges/block. te@cand_W[0:128] via LDS-staged mini-GEMM; then
// lrelu(acc + relCand[er] + hnewCand[tn]) . rank_W[0:256] + qdot[bi] + rank_b.
__global__ __launch_bounds__(256) void score_k(
    const float* __restrict__ entity_emb, const float* __restrict__ cand_W,
    const float* __restrict__ relCand, const float* __restrict__ hnewCand,
    const float* __restrict__ rank_W, const float* __restrict__ rank_b_p,
    const float* __restrict__ qdot, const int* __restrict__ tail_ent,
    const int* __restrict__ edge_rel, const int* __restrict__ tail_node,
    const int* __restrict__ batch_idx, float* __restrict__ scores)
{
    const int tid = threadIdx.x;
    const int e0 = blockIdx.x * 32;
    __shared__ int s_te[32], s_er[32], s_tn[32], s_bi[32];
    __shared__ float te_lds[32][128];
    if (tid < 32) {
        int e = e0 + tid;
        s_te[tid] = tail_ent[e]; s_er[tid] = edge_rel[e];
        s_tn[tid] = tail_node[e]; s_bi[tid] = batch_idx[e];
    }
    __syncthreads();
    #pragma unroll
    for (int r = 0; r < 4; ++r) {
        int f = tid + r * 256;
        int i = f >> 5, c4 = (f & 31) * 4;
        float4 v = *(const float4*)(entity_emb + (size_t)s_te[i] * 128 + c4);
        *(float4*)&te_lds[i][c4] = v;
    }
    __syncthreads();
    const int tx = tid & 63, ty = tid >> 6;
    const int c = tx * 4;
    float acc[8][4] = {};
    #pragma unroll 2
    for (int k4 = 0; k4 < 128; k4 += 4) {
        float4 w0 = *(const float4*)(cand_W + (size_t)(k4 + 0) * 256 + c);
        float4 w1 = *(const float4*)(cand_W + (size_t)(k4 + 1) * 256 + c);
        float4 w2 = *(const float4*)(cand_W + (size_t)(k4 + 2) * 256 + c);
        float4 w3 = *(const float4*)(cand_W + (size_t)(k4 + 3) * 256 + c);
        #pragma unroll
        for (int i2 = 0; i2 < 8; ++i2) {
            int i = ty * 8 + i2;
            float4 t = *(const float4*)&te_lds[i][k4];
            acc[i2][0] += t.x * w0.x + t.y * w1.x + t.z * w2.x + t.w * w3.x;
            acc[i2][1] += t.x * w0.y + t.y * w1.y + t.z * w2.y + t.w * w3.y;
            acc[i2][2] += t.x * w0.z + t.y * w1.z + t.z * w2.z + t.w * w3.z;
            acc[i2][3] += t.x * w0.w + t.y * w1.w + t.z * w2.w + t.w * w3.w;
        }
    }
    const float4 rw = *(const float4*)(rank_W + c);
    float part[8];
    #pragma unroll
    for (int i2 = 0; i2 < 8; ++i2) {
        int i = ty * 8 + i2;
        float4 rc = *(const float4*)(relCand + (size_t)s_er[i] * 256 + c);
        float4 hc = *(const float4*)(hnewCand + (size_t)s_tn[i] * 256 + c);
        float v0 = acc[i2][0] + rc.x + hc.x; v0 = v0 > 0.f ? v0 : 0.01f * v0;
        float v1 = acc[i2][1] + rc.y + hc.y; v1 = v1 > 0.f ? v1 : 0.01f * v1;
        float v2 = acc[i2][2] + rc.z + hc.z; v2 = v2 > 0.f ? v2 : 0.01f * v2;
        float v3 = acc[i2][3] + rc.w + hc.w; v3 = v3 > 0.f ? v3 : 0.01f * v3;
        part[i2] = v0 * rw.x + v1 * rw.y + v2 * rw.z + v3 * rw.w;
    }
    #pragma unroll
    for (int off = 32; off; off >>= 1)
        #pragma unroll
        for (int i2 = 0; i2 < 8; ++i2)
            part[i2] += __shfl_xor(part[i2], off, 64);
    if (tx == 0) {
        float rb = rank_b_p[0];
        #pragma unroll
        for (int i2 = 0; i2 < 8; ++i2) {
            int i = ty * 8 + i2;
            scores[e0 + i] = part[i2] + qdot[s_bi[i]] + rb;
        }
    }
}

// ---------------------------------------------------------------------------
extern "C" void kernel_launch(void* const* d_in, const int* in_sizes, int n_in,
                              void* d_out, int out_size, void* d_ws, size_t ws_size,
                              hipStream_t stream)
{
    const float* entity_emb   = (const float*)d_in[0];
    const float* relation_emb = (const float*)d_in[1];
    const float* node_hidden  = (const float*)d_in[2];
    const float* query_repr   = (const float*)d_in[3];
    const float* Ws    = (const float*)d_in[4];
    const float* Wr    = (const float*)d_in[5];
    const float* Wqr   = (const float*)d_in[6];
    const float* bqr   = (const float*)d_in[7];
    const float* w_alpha = (const float*)d_in[8];
    const float* b_alpha = (const float*)d_in[9];
    const float* W_ih  = (const float*)d_in[10];
    const float* W_hh  = (const float*)d_in[11];
    const float* b_ih  = (const float*)d_in[12];
    const float* b_hh  = (const float*)d_in[13];
    const float* We2h_W = (const float*)d_in[14];
    const float* We2h_b = (const float*)d_in[15];
    const float* cand_W = (const float*)d_in[16];
    const float* cand_b = (const float*)d_in[17];
    const float* rank_W = (const float*)d_in[18];
    const float* rank_b = (const float*)d_in[19];
    const float* ln_g  = (const float*)d_in[20];
    const float* ln_b  = (const float*)d_in[21];
    const int* head_node = (const int*)d_in[22];
    const int* edge_rel  = (const int*)d_in[23];
    const int* tail_ent  = (const int*)d_in[24];
    const int* tail_node = (const int*)d_in[25];
    const int* query_rel = (const int*)d_in[26];
    const int* batch_idx = (const int*)d_in[27];
    const int* tail_node_ent = (const int*)d_in[28];
    float* out = (float*)d_out;
    (void)in_sizes; (void)n_in; (void)out_size; (void)ws_size;

    const int M = 200000, NNEW = 50000, NNODES = 100000, NREL = 500;
    const int NCHUNK = 4, NC = NNEW / NCHUNK;   // 12500

    // ---- workspace layout (floats) ----
    float* w = (float*)d_ws;
    float* relWr    = w; w += NREL * 256;
    float* relWqr   = w; w += NREL * 256;
    float* relCand  = w; w += NREL * 256;
    float* W_ihT    = w; w += 256 * 768;
    float* W_hhT    = w; w += 256 * 768;
    float* qdot     = w; w += 256;
    float* alpha    = w; w += M;
    float* h_prev   = w; w += (size_t)NNEW * 256;
    float* agg      = w; w += (size_t)NNEW * 256;
    float* h_new    = w; w += (size_t)NNEW * 256;
    float* hnewCand = w; w += (size_t)NNEW * 256;
    float* big      = w; w += (size_t)NNODES * 256;   // nodeWs, later gx|gh
    float* nodeWs = big;
    float* gx_buf = big;
    float* gh_buf = big + (size_t)NC * 768;

    // (1) weight transposes + per-relation tables + qdot
    transpose_k<<<768, 256, 0, stream>>>(W_ih, W_ihT);
    transpose_k<<<768, 256, 0, stream>>>(W_hh, W_hhT);
    gemm_k<<<dim3(8, 4), 256, 0, stream>>>(relation_emb, Wr,  nullptr, relWr,  NREL, 256, 128, nullptr, ACT_NONE);
    gemm_k<<<dim3(8, 4), 256, 0, stream>>>(relation_emb, Wqr, nullptr, relWqr, NREL, 256, 128, nullptr, ACT_NONE);
    gemm_k<<<dim3(8, 4), 256, 0, stream>>>(relation_emb, cand_W + 128 * 256, nullptr, relCand, NREL, 256, 128, nullptr, ACT_NONE);
    qdot_k<<<64, 256, 0, stream>>>(query_repr, rank_W, qdot);

    // (2) nodeWs = node_hidden @ Ws
    gemm_k<<<dim3((NNODES + 63) / 64, 4), 256, 0, stream>>>(node_hidden, Ws, nullptr, nodeWs, NNODES, 256, 256, nullptr, ACT_NONE);

    // (3) alpha
    alpha_k<<<M / 32, 256, 0, stream>>>(nodeWs, relWr, relWqr, bqr, w_alpha, b_alpha,
                                        head_node, edge_rel, query_rel, alpha);

    // (4) segment sum
    hipMemsetAsync(agg, 0, (size_t)NNEW * 256 * sizeof(float), stream);
    scatter_k<<<M * 64 / 256, 256, 0, stream>>>(relation_emb, entity_emb, alpha,
                                                edge_rel, tail_ent, tail_node, agg);

    // (5) h_prev = lrelu(entity_emb[tail_node_ent] @ We2h_W + We2h_b)
    gemm_k<<<dim3((NNEW + 63) / 64, 4), 256, 0, stream>>>(entity_emb, We2h_W, We2h_b, h_prev,
                                                          NNEW, 256, 128, tail_node_ent, ACT_LRELU);

    // (6,7) GRU, chunked so gx/gh reuse the nodeWs region
    for (int ch = 0; ch < NCHUNK; ++ch) {
        int n0 = ch * NC;
        gemm_k<<<dim3((NC + 63) / 64, 12), 256, 0, stream>>>(agg + (size_t)n0 * 256, W_ihT, b_ih, gx_buf,
                                                             NC, 768, 256, nullptr, ACT_NONE);
        gemm_k<<<dim3((NC + 63) / 64, 12), 256, 0, stream>>>(h_prev + (size_t)n0 * 256, W_hhT, b_hh, gh_buf,
                                                             NC, 768, 256, nullptr, ACT_NONE);
        gru_ln_k<<<NC / 4, 256, 0, stream>>>(gx_buf, gh_buf, h_prev, ln_g, ln_b, h_new, n0);
    }

    // (8) hnewCand = h_new @ cand_W[256:512] + cand_b  (lrelu deferred to score)
    gemm_k<<<dim3((NNEW + 63) / 64, 4), 256, 0, stream>>>(h_new, cand_W + 256 * 256, cand_b, hnewCand,
                                                          NNEW, 256, 256, nullptr, ACT_NONE);

    // (9) scores
    score_k<<<M / 32, 256, 0, stream>>>(entity_emb, cand_W, relCand, hnewCand,
                                        rank_W, rank_b, qdot, tail_ent, edge_rel,
                                        tail_node, batch_idx, out);
}

// Round 2
// 1553.082 us; speedup vs baseline: 1.3855x; 1.3855x over previous
//
#include <hip/hip_runtime.h>
#include <math.h>

// ---------------------------------------------------------------------------
// CogKR scoring pipeline, fp32, algebraic factorization + CSR segment-sum.
// R1 -> R2 change: scatter_k (51.2M fp32 atomics, 819MB HBM write-through,
// 675us) replaced by CSR build (hist + 3-pass scan + fill) + per-node
// gather-reduce agg_csr_k. Everything else unchanged.
// ---------------------------------------------------------------------------

#define ACT_NONE 0
#define ACT_LRELU 1

// ---------------- generic tiled fp32 GEMM: C = act(A@B + bias) ----------------
__global__ __launch_bounds__(256) void gemm_k(
    const float* __restrict__ A, const float* __restrict__ B,
    const float* __restrict__ bias, float* __restrict__ C,
    int M, int N, int K, const int* __restrict__ a_idx, int act)
{
    __shared__ float As[16][68];
    __shared__ float Bs[16][68];
    const int tid = threadIdx.x;
    const int tx = tid & 15, ty = tid >> 4;
    const int m0 = blockIdx.x * 64, n0 = blockIdx.y * 64;

    float acc[4][4] = {};

    const int ar  = tid >> 2;
    const int ac4 = (tid & 3) * 4;
    const int brow = tid >> 4;
    const int bc4  = (tid & 15) * 4;

    const int gm = m0 + ar;
    const float* Arow = nullptr;
    if (gm < M) {
        int r = a_idx ? a_idx[gm] : gm;
        Arow = A + (size_t)r * K;
    }

    for (int k0 = 0; k0 < K; k0 += 16) {
        float4 av = make_float4(0.f, 0.f, 0.f, 0.f);
        if (Arow) av = *(const float4*)(Arow + k0 + ac4);
        As[ac4 + 0][ar] = av.x;
        As[ac4 + 1][ar] = av.y;
        As[ac4 + 2][ar] = av.z;
        As[ac4 + 3][ar] = av.w;
        float4 bv = *(const float4*)(B + (size_t)(k0 + brow) * N + n0 + bc4);
        *(float4*)&Bs[brow][bc4] = bv;
        __syncthreads();
        #pragma unroll
        for (int kk = 0; kk < 16; ++kk) {
            float4 a4 = *(float4*)&As[kk][ty << 2];
            float4 b4 = *(float4*)&Bs[kk][tx << 2];
            float avr[4] = {a4.x, a4.y, a4.z, a4.w};
            float bvr[4] = {b4.x, b4.y, b4.z, b4.w};
            #pragma unroll
            for (int i = 0; i < 4; ++i)
                #pragma unroll
                for (int j = 0; j < 4; ++j)
                    acc[i][j] = fmaf(avr[i], bvr[j], acc[i][j]);
        }
        __syncthreads();
    }

    const int n = n0 + (tx << 2);
    float4 bv4 = make_float4(0.f, 0.f, 0.f, 0.f);
    if (bias) bv4 = *(const float4*)(bias + n);
    #pragma unroll
    for (int i = 0; i < 4; ++i) {
        int m = m0 + (ty << 2) + i;
        if (m >= M) continue;
        float v0 = acc[i][0] + bv4.x;
        float v1 = acc[i][1] + bv4.y;
        float v2 = acc[i][2] + bv4.z;
        float v3 = acc[i][3] + bv4.w;
        if (act == ACT_LRELU) {
            v0 = v0 > 0.f ? v0 : 0.01f * v0;
            v1 = v1 > 0.f ? v1 : 0.01f * v1;
            v2 = v2 > 0.f ? v2 : 0.01f * v2;
            v3 = v3 > 0.f ? v3 : 0.01f * v3;
        }
        float4 out = make_float4(v0, v1, v2, v3);
        *(float4*)(C + (size_t)m * N + n) = out;
    }
}

// ---------------- transpose 768x256 -> 256x768 ----------------
__global__ __launch_bounds__(256) void transpose_k(
    const float* __restrict__ in, float* __restrict__ out)
{
    int t = blockIdx.x * 256 + threadIdx.x;
    int r = t >> 8, c = t & 255;
    out[(size_t)c * 768 + r] = in[t];
}

// ---------------- qdot[b] = query_repr[b] . rank_W[256:512] ----------------
__global__ __launch_bounds__(256) void qdot_k(
    const float* __restrict__ q, const float* __restrict__ rank_W,
    float* __restrict__ qdot)
{
    int b = blockIdx.x * 4 + (threadIdx.x >> 6);
    int l = threadIdx.x & 63;
    float s = 0.f;
    #pragma unroll
    for (int k = 0; k < 4; ++k) {
        int h = l + k * 64;
        s += q[(size_t)b * 256 + h] * rank_W[256 + h];
    }
    #pragma unroll
    for (int off = 32; off; off >>= 1) s += __shfl_xor(s, off, 64);
    if (l == 0) qdot[b] = s;
}

// ---------------- per-edge attention alpha ----------------
__global__ __launch_bounds__(256) void alpha_k(
    const float* __restrict__ nodeWs, const float* __restrict__ relWr,
    const float* __restrict__ relWqr, const float* __restrict__ bqr,
    const float* __restrict__ w_alpha, const float* __restrict__ b_alpha_p,
    const int* __restrict__ head_node, const int* __restrict__ edge_rel,
    const int* __restrict__ query_rel, float* __restrict__ alpha_out)
{
    const int tid = threadIdx.x;
    const int e0 = blockIdx.x * 32;
    __shared__ int hn[32], er[32], qr[32];
    if (tid < 32) {
        int e = e0 + tid;
        hn[tid] = head_node[e]; er[tid] = edge_rel[e]; qr[tid] = query_rel[e];
    }
    __syncthreads();
    const int tx = tid & 63, ty = tid >> 6;
    const int c = tx * 4;
    const float4 bq = *(const float4*)(bqr + c);
    const float4 wa = *(const float4*)(w_alpha + c);
    float part[8];
    #pragma unroll
    for (int i2 = 0; i2 < 8; ++i2) {
        int i = ty * 8 + i2;
        float4 a = *(const float4*)(nodeWs + (size_t)hn[i] * 256 + c);
        float4 b = *(const float4*)(relWr + (size_t)er[i] * 256 + c);
        float4 d = *(const float4*)(relWqr + (size_t)qr[i] * 256 + c);
        float x0 = fmaxf(a.x + b.x + d.x + bq.x, 0.f);
        float x1 = fmaxf(a.y + b.y + d.y + bq.y, 0.f);
        float x2 = fmaxf(a.z + b.z + d.z + bq.z, 0.f);
        float x3 = fmaxf(a.w + b.w + d.w + bq.w, 0.f);
        part[i2] = x0 * wa.x + x1 * wa.y + x2 * wa.z + x3 * wa.w;
    }
    #pragma unroll
    for (int off = 32; off; off >>= 1)
        #pragma unroll
        for (int i2 = 0; i2 < 8; ++i2)
            part[i2] += __shfl_xor(part[i2], off, 64);
    if (tx == 0) {
        float ba = b_alpha_p[0];
        #pragma unroll
        for (int i2 = 0; i2 < 8; ++i2)
            alpha_out[e0 + ty * 8 + i2] = 1.f / (1.f + __expf(-(part[i2] + ba)));
    }
}

// ---------------- CSR build: histogram ----------------
__global__ __launch_bounds__(256) void hist_k(
    const int* __restrict__ tail_node, int* __restrict__ deg, int M)
{
    int e = blockIdx.x * 256 + threadIdx.x;
    if (e < M) atomicAdd(&deg[tail_node[e]], 1);
}

// ---------------- scan pass 1: per-block sums (256 elems/block) ----------------
__global__ __launch_bounds__(256) void scan1_k(
    const int* __restrict__ deg, int* __restrict__ partial, int N)
{
    __shared__ int sm[256];
    int i = blockIdx.x * 256 + threadIdx.x;
    int v = (i < N) ? deg[i] : 0;
    sm[threadIdx.x] = v;
    __syncthreads();
    for (int off = 128; off; off >>= 1) {
        if (threadIdx.x < off) sm[threadIdx.x] += sm[threadIdx.x + off];
        __syncthreads();
    }
    if (threadIdx.x == 0) partial[blockIdx.x] = sm[0];
}

// ---------------- scan pass 2: exclusive scan of partials (1 block) ----------------
__global__ __launch_bounds__(256) void scan2_k(
    int* __restrict__ partial, int nPart, int* __restrict__ offsets, int N, int M)
{
    __shared__ int sm[256];
    int t = threadIdx.x;
    int v = (t < nPart) ? partial[t] : 0;
    sm[t] = v;
    __syncthreads();
    // inclusive Hillis-Steele
    for (int off = 1; off < 256; off <<= 1) {
        int add = (t >= off) ? sm[t - off] : 0;
        __syncthreads();
        sm[t] += add;
        __syncthreads();
    }
    if (t < nPart) partial[t] = sm[t] - v;   // exclusive
    if (t == 0) offsets[N] = M;
}

// ---------------- scan pass 3: per-element exclusive scan + cursor copy ----------------
__global__ __launch_bounds__(256) void scan3_k(
    const int* __restrict__ deg, const int* __restrict__ partial,
    int* __restrict__ offsets, int* __restrict__ cursor, int N)
{
    __shared__ int sm[256];
    int i = blockIdx.x * 256 + threadIdx.x;
    int t = threadIdx.x;
    int v = (i < N) ? deg[i] : 0;
    sm[t] = v;
    __syncthreads();
    for (int off = 1; off < 256; off <<= 1) {
        int add = (t >= off) ? sm[t - off] : 0;
        __syncthreads();
        sm[t] += add;
        __syncthreads();
    }
    if (i < N) {
        int excl = partial[blockIdx.x] + sm[t] - v;
        offsets[i] = excl;
        cursor[i] = excl;
    }
}

// ---------------- CSR fill ----------------
__global__ __launch_bounds__(256) void fill_k(
    const int* __restrict__ tail_node, int* __restrict__ cursor,
    int* __restrict__ csr, int M)
{
    int e = blockIdx.x * 256 + threadIdx.x;
    if (e < M) {
        int pos = atomicAdd(&cursor[tail_node[e]], 1);
        csr[pos] = e;
    }
}

// ---------------- segment-sum via CSR gather-reduce ----------------
// One wave per tail node; lane covers cols 4l..4l+3; no atomics.
__global__ __launch_bounds__(256) void agg_csr_k(
    const float* __restrict__ relation_emb, const float* __restrict__ entity_emb,
    const float* __restrict__ alpha, const int* __restrict__ edge_rel,
    const int* __restrict__ tail_ent, const int* __restrict__ offsets,
    const int* __restrict__ csr, float* __restrict__ agg)
{
    int node = blockIdx.x * 4 + (threadIdx.x >> 6);
    int lane = threadIdx.x & 63;
    int beg = offsets[node], end = offsets[node + 1];
    int c = lane * 4;
    float4 acc = make_float4(0.f, 0.f, 0.f, 0.f);
    for (int j = beg; j < end; ++j) {
        int e = csr[j];
        float a = alpha[e];
        const float* src = (c < 128)
            ? (relation_emb + (size_t)edge_rel[e] * 128 + c)
            : (entity_emb + (size_t)tail_ent[e] * 128 + (c - 128));
        float4 v = *(const float4*)src;
        acc.x += v.x * a; acc.y += v.y * a;
        acc.z += v.z * a; acc.w += v.w * a;
    }
    *(float4*)(agg + (size_t)node * 256 + c) = acc;
}

// ---------------- GRU elementwise + LayerNorm ----------------
__global__ __launch_bounds__(256) void gru_ln_k(
    const float* __restrict__ gx, const float* __restrict__ gh,
    const float* __restrict__ h_prev, const float* __restrict__ ln_g,
    const float* __restrict__ ln_b, float* __restrict__ h_new, int n0)
{
    int nl = blockIdx.x * 4 + (threadIdx.x >> 6);
    int lane = threadIdx.x & 63;
    int n = n0 + nl;
    const float* gxr = gx + (size_t)nl * 768;
    const float* ghr = gh + (size_t)nl * 768;
    const float* hpr = h_prev + (size_t)n * 256;
    float hv[4]; float s = 0.f, s2 = 0.f;
    #pragma unroll
    for (int q2 = 0; q2 < 4; ++q2) {
        int h = lane + q2 * 64;
        float xr = gxr[h], xz = gxr[256 + h], xn = gxr[512 + h];
        float hr_ = ghr[h], hz_ = ghr[256 + h], hn_ = ghr[512 + h];
        float hp = hpr[h];
        float r = 1.f / (1.f + __expf(-(xr + hr_)));
        float z = 1.f / (1.f + __expf(-(xz + hz_)));
        float nn = tanhf(xn + r * hn_);
        float v = (1.f - z) * nn + z * hp;
        hv[q2] = v; s += v; s2 += v * v;
    }
    #pragma unroll
    for (int off = 32; off; off >>= 1) {
        s  += __shfl_xor(s, off, 64);
        s2 += __shfl_xor(s2, off, 64);
    }
    float mean = s * (1.f / 256.f);
    float var  = s2 * (1.f / 256.f) - mean * mean;
    float rstd = rsqrtf(var + 1e-5f);
    float* outr = h_new + (size_t)n * 256;
    #pragma unroll
    for (int q2 = 0; q2 < 4; ++q2) {
        int h = lane + q2 * 64;
        outr[h] = (hv[q2] - mean) * rstd * ln_g[h] + ln_b[h];
    }
}

// ---------------- per-edge candidate + rank scoring ----------------
__global__ __launch_bounds__(256) void score_k(
    const float* __restrict__ entity_emb, const float* __restrict__ cand_W,
    const float* __restrict__ relCand, const float* __restrict__ hnewCand,
    const float* __restrict__ rank_W, const float* __restrict__ rank_b_p,
    const float* __restrict__ qdot, const int* __restrict__ tail_ent,
    const int* __restrict__ edge_rel, const int* __restrict__ tail_node,
    const int* __restrict__ batch_idx, float* __restrict__ scores)
{
    const int tid = threadIdx.x;
    const int e0 = blockIdx.x * 32;
    __shared__ int s_te[32], s_er[32], s_tn[32], s_bi[32];
    __shared__ float te_lds[32][128];
    if (tid < 32) {
        int e = e0 + tid;
        s_te[tid] = tail_ent[e]; s_er[tid] = edge_rel[e];
        s_tn[tid] = tail_node[e]; s_bi[tid] = batch_idx[e];
    }
    __syncthreads();
    #pragma unroll
    for (int r = 0; r < 4; ++r) {
        int f = tid + r * 256;
        int i = f >> 5, c4 = (f & 31) * 4;
        float4 v = *(const float4*)(entity_emb + (size_t)s_te[i] * 128 + c4);
        *(float4*)&te_lds[i][c4] = v;
    }
    __syncthreads();
    const int tx = tid & 63, ty = tid >> 6;
    const int c = tx * 4;
    float acc[8][4] = {};
    #pragma unroll 2
    for (int k4 = 0; k4 < 128; k4 += 4) {
        float4 w0 = *(const float4*)(cand_W + (size_t)(k4 + 0) * 256 + c);
        float4 w1 = *(const float4*)(cand_W + (size_t)(k4 + 1) * 256 + c);
        float4 w2 = *(const float4*)(cand_W + (size_t)(k4 + 2) * 256 + c);
        float4 w3 = *(const float4*)(cand_W + (size_t)(k4 + 3) * 256 + c);
        #pragma unroll
        for (int i2 = 0; i2 < 8; ++i2) {
            int i = ty * 8 + i2;
            float4 t = *(const float4*)&te_lds[i][k4];
            acc[i2][0] += t.x * w0.x + t.y * w1.x + t.z * w2.x + t.w * w3.x;
            acc[i2][1] += t.x * w0.y + t.y * w1.y + t.z * w2.y + t.w * w3.y;
            acc[i2][2] += t.x * w0.z + t.y * w1.z + t.z * w2.z + t.w * w3.z;
            acc[i2][3] += t.x * w0.w + t.y * w1.w + t.z * w2.w + t.w * w3.w;
        }
    }
    const float4 rw = *(const float4*)(rank_W + c);
    float part[8];
    #pragma unroll
    for (int i2 = 0; i2 < 8; ++i2) {
        int i = ty * 8 + i2;
        float4 rc = *(const float4*)(relCand + (size_t)s_er[i] * 256 + c);
        float4 hc = *(const float4*)(hnewCand + (size_t)s_tn[i] * 256 + c);
        float v0 = acc[i2][0] + rc.x + hc.x; v0 = v0 > 0.f ? v0 : 0.01f * v0;
        float v1 = acc[i2][1] + rc.y + hc.y; v1 = v1 > 0.f ? v1 : 0.01f * v1;
        float v2 = acc[i2][2] + rc.z + hc.z; v2 = v2 > 0.f ? v2 : 0.01f * v2;
        float v3 = acc[i2][3] + rc.w + hc.w; v3 = v3 > 0.f ? v3 : 0.01f * v3;
        part[i2] = v0 * rw.x + v1 * rw.y + v2 * rw.z + v3 * rw.w;
    }
    #pragma unroll
    for (int off = 32; off; off >>= 1)
        #pragma unroll
        for (int i2 = 0; i2 < 8; ++i2)
            part[i2] += __shfl_xor(part[i2], off, 64);
    if (tx == 0) {
        float rb = rank_b_p[0];
        #pragma unroll
        for (int i2 = 0; i2 < 8; ++i2) {
            int i = ty * 8 + i2;
            scores[e0 + i] = part[i2] + qdot[s_bi[i]] + rb;
        }
    }
}

// ---------------------------------------------------------------------------
extern "C" void kernel_launch(void* const* d_in, const int* in_sizes, int n_in,
                              void* d_out, int out_size, void* d_ws, size_t ws_size,
                              hipStream_t stream)
{
    const float* entity_emb   = (const float*)d_in[0];
    const float* relation_emb = (const float*)d_in[1];
    const float* node_hidden  = (const float*)d_in[2];
    const float* query_repr   = (const float*)d_in[3];
    const float* Ws    = (const float*)d_in[4];
    const float* Wr    = (const float*)d_in[5];
    const float* Wqr   = (const float*)d_in[6];
    const float* bqr   = (const float*)d_in[7];
    const float* w_alpha = (const float*)d_in[8];
    const float* b_alpha = (const float*)d_in[9];
    const float* W_ih  = (const float*)d_in[10];
    const float* W_hh  = (const float*)d_in[11];
    const float* b_ih  = (const float*)d_in[12];
    const float* b_hh  = (const float*)d_in[13];
    const float* We2h_W = (const float*)d_in[14];
    const float* We2h_b = (const float*)d_in[15];
    const float* cand_W = (const float*)d_in[16];
    const float* cand_b = (const float*)d_in[17];
    const float* rank_W = (const float*)d_in[18];
    const float* rank_b = (const float*)d_in[19];
    const float* ln_g  = (const float*)d_in[20];
    const float* ln_b  = (const float*)d_in[21];
    const int* head_node = (const int*)d_in[22];
    const int* edge_rel  = (const int*)d_in[23];
    const int* tail_ent  = (const int*)d_in[24];
    const int* tail_node = (const int*)d_in[25];
    const int* query_rel = (const int*)d_in[26];
    const int* batch_idx = (const int*)d_in[27];
    const int* tail_node_ent = (const int*)d_in[28];
    float* out = (float*)d_out;
    (void)in_sizes; (void)n_in; (void)out_size; (void)ws_size;

    const int M = 200000, NNEW = 50000, NNODES = 100000, NREL = 500;
    const int NCHUNK = 4, NC = NNEW / NCHUNK;   // 12500
    const int NPART = (NNEW + 255) / 256;       // 196

    // ---- workspace layout ----
    float* w = (float*)d_ws;
    float* relWr    = w; w += NREL * 256;
    float* relWqr   = w; w += NREL * 256;
    float* relCand  = w; w += NREL * 256;
    float* W_ihT    = w; w += 256 * 768;
    float* W_hhT    = w; w += 256 * 768;
    float* qdot     = w; w += 256;
    float* alpha    = w; w += M;
    float* h_prev   = w; w += (size_t)NNEW * 256;
    float* agg      = w; w += (size_t)NNEW * 256;
    float* h_new    = w; w += (size_t)NNEW * 256;
    float* hnewCand = w; w += (size_t)NNEW * 256;
    // CSR scratch (ints)
    int* deg     = (int*)w; w += NNEW;
    int* offsets = (int*)w; w += NNEW + 1;
    int* cursor  = (int*)w; w += NNEW;
    int* partial = (int*)w; w += 256;
    int* csr     = (int*)w; w += M;
    float* big      = w; w += (size_t)NNODES * 256;   // nodeWs, later gx|gh
    float* nodeWs = big;
    float* gx_buf = big;
    float* gh_buf = big + (size_t)NC * 768;

    // (0) CSR build (independent of float pipeline; overlaps fine)
    hipMemsetAsync(deg, 0, NNEW * sizeof(int), stream);
    hist_k<<<(M + 255) / 256, 256, 0, stream>>>(tail_node, deg, M);
    scan1_k<<<NPART, 256, 0, stream>>>(deg, partial, NNEW);
    scan2_k<<<1, 256, 0, stream>>>(partial, NPART, offsets, NNEW, M);
    scan3_k<<<NPART, 256, 0, stream>>>(deg, partial, offsets, cursor, NNEW);
    fill_k<<<(M + 255) / 256, 256, 0, stream>>>(tail_node, cursor, csr, M);

    // (1) weight transposes + per-relation tables + qdot
    transpose_k<<<768, 256, 0, stream>>>(W_ih, W_ihT);
    transpose_k<<<768, 256, 0, stream>>>(W_hh, W_hhT);
    gemm_k<<<dim3(8, 4), 256, 0, stream>>>(relation_emb, Wr,  nullptr, relWr,  NREL, 256, 128, nullptr, ACT_NONE);
    gemm_k<<<dim3(8, 4), 256, 0, stream>>>(relation_emb, Wqr, nullptr, relWqr, NREL, 256, 128, nullptr, ACT_NONE);
    gemm_k<<<dim3(8, 4), 256, 0, stream>>>(relation_emb, cand_W + 128 * 256, nullptr, relCand, NREL, 256, 128, nullptr, ACT_NONE);
    qdot_k<<<64, 256, 0, stream>>>(query_repr, rank_W, qdot);

    // (2) nodeWs = node_hidden @ Ws
    gemm_k<<<dim3((NNODES + 63) / 64, 4), 256, 0, stream>>>(node_hidden, Ws, nullptr, nodeWs, NNODES, 256, 256, nullptr, ACT_NONE);

    // (3) alpha
    alpha_k<<<M / 32, 256, 0, stream>>>(nodeWs, relWr, relWqr, bqr, w_alpha, b_alpha,
                                        head_node, edge_rel, query_rel, alpha);

    // (4) segment sum via CSR gather-reduce (no atomics on agg)
    agg_csr_k<<<NNEW / 4, 256, 0, stream>>>(relation_emb, entity_emb, alpha,
                                            edge_rel, tail_ent, offsets, csr, agg);

    // (5) h_prev = lrelu(entity_emb[tail_node_ent] @ We2h_W + We2h_b)
    gemm_k<<<dim3((NNEW + 63) / 64, 4), 256, 0, stream>>>(entity_emb, We2h_W, We2h_b, h_prev,
                                                          NNEW, 256, 128, tail_node_ent, ACT_LRELU);

    // (6,7) GRU, chunked so gx/gh reuse the nodeWs region
    for (int ch = 0; ch < NCHUNK; ++ch) {
        int n0 = ch * NC;
        gemm_k<<<dim3((NC + 63) / 64, 12), 256, 0, stream>>>(agg + (size_t)n0 * 256, W_ihT, b_ih, gx_buf,
                                                             NC, 768, 256, nullptr, ACT_NONE);
        gemm_k<<<dim3((NC + 63) / 64, 12), 256, 0, stream>>>(h_prev + (size_t)n0 * 256, W_hhT, b_hh, gh_buf,
                                                             NC, 768, 256, nullptr, ACT_NONE);
        gru_ln_k<<<NC / 4, 256, 0, stream>>>(gx_buf, gh_buf, h_prev, ln_g, ln_b, h_new, n0);
    }

    // (8) hnewCand = h_new @ cand_W[256:512] + cand_b
    gemm_k<<<dim3((NNEW + 63) / 64, 4), 256, 0, stream>>>(h_new, cand_W + 256 * 256, cand_b, hnewCand,
                                                          NNEW, 256, 256, nullptr, ACT_NONE);

    // (9) scores
    score_k<<<M / 32, 256, 0, stream>>>(entity_emb, cand_W, relCand, hnewCand,
                                        rank_W, rank_b, qdot, tail_ent, edge_rel,
                                        tail_node, batch_idx, out);
}

// Round 3
// 1079.433 us; speedup vs baseline: 1.9934x; 1.4388x over previous
//
#include <hip/hip_runtime.h>
#include <math.h>

// ---------------------------------------------------------------------------
// CogKR pipeline, R3: all GEMM-shaped work moved to bf16 MFMA (16x16x32),
// fp32 accumulate. A-operands converted fp32->bf16 during LDS staging;
// weights pre-converted to B^T [N,K] bf16 once per launch. score_k fully
// fused as a 64-edge/block MFMA kernel with in-block rank reduction.
// CSR segment-sum unchanged from R2. ws ~287 MB.
// ---------------------------------------------------------------------------

#define ACT_NONE 0
#define ACT_LRELU 1

typedef __attribute__((ext_vector_type(8))) short short8;
typedef __attribute__((ext_vector_type(4))) float floatx4;

__device__ __forceinline__ ushort f2b(float x) {
    union { float f; unsigned u; } v; v.f = x;
    return (ushort)((v.u + 0x7fffu + ((v.u >> 16) & 1u)) >> 16);
}
__device__ __forceinline__ float b2f(ushort b) {
    union { unsigned u; float f; } v; v.u = ((unsigned)b) << 16;
    return v.f;
}

// ---------------- small fp32 tiled GEMM (relation tables only) ----------------
__global__ __launch_bounds__(256) void gemm_k(
    const float* __restrict__ A, const float* __restrict__ B,
    const float* __restrict__ bias, float* __restrict__ C,
    int M, int N, int K, const int* __restrict__ a_idx, int act)
{
    __shared__ float As[16][68];
    __shared__ float Bs[16][68];
    const int tid = threadIdx.x;
    const int tx = tid & 15, ty = tid >> 4;
    const int m0 = blockIdx.x * 64, n0 = blockIdx.y * 64;
    float acc[4][4] = {};
    const int ar  = tid >> 2;
    const int ac4 = (tid & 3) * 4;
    const int brow = tid >> 4;
    const int bc4  = (tid & 15) * 4;
    const int gm = m0 + ar;
    const float* Arow = nullptr;
    if (gm < M) {
        int r = a_idx ? a_idx[gm] : gm;
        Arow = A + (size_t)r * K;
    }
    for (int k0 = 0; k0 < K; k0 += 16) {
        float4 av = make_float4(0.f, 0.f, 0.f, 0.f);
        if (Arow) av = *(const float4*)(Arow + k0 + ac4);
        As[ac4 + 0][ar] = av.x;
        As[ac4 + 1][ar] = av.y;
        As[ac4 + 2][ar] = av.z;
        As[ac4 + 3][ar] = av.w;
        float4 bv = *(const float4*)(B + (size_t)(k0 + brow) * N + n0 + bc4);
        *(float4*)&Bs[brow][bc4] = bv;
        __syncthreads();
        #pragma unroll
        for (int kk = 0; kk < 16; ++kk) {
            float4 a4 = *(float4*)&As[kk][ty << 2];
            float4 b4 = *(float4*)&Bs[kk][tx << 2];
            float avr[4] = {a4.x, a4.y, a4.z, a4.w};
            float bvr[4] = {b4.x, b4.y, b4.z, b4.w};
            #pragma unroll
            for (int i = 0; i < 4; ++i)
                #pragma unroll
                for (int j = 0; j < 4; ++j)
                    acc[i][j] = fmaf(avr[i], bvr[j], acc[i][j]);
        }
        __syncthreads();
    }
    const int n = n0 + (tx << 2);
    float4 bv4 = make_float4(0.f, 0.f, 0.f, 0.f);
    if (bias) bv4 = *(const float4*)(bias + n);
    #pragma unroll
    for (int i = 0; i < 4; ++i) {
        int m = m0 + (ty << 2) + i;
        if (m >= M) continue;
        float v0 = acc[i][0] + bv4.x;
        float v1 = acc[i][1] + bv4.y;
        float v2 = acc[i][2] + bv4.z;
        float v3 = acc[i][3] + bv4.w;
        if (act == ACT_LRELU) {
            v0 = v0 > 0.f ? v0 : 0.01f * v0;
            v1 = v1 > 0.f ? v1 : 0.01f * v1;
            v2 = v2 > 0.f ? v2 : 0.01f * v2;
            v3 = v3 > 0.f ? v3 : 0.01f * v3;
        }
        *(float4*)(C + (size_t)m * N + n) = make_float4(v0, v1, v2, v3);
    }
}

// ---------------- weight prep: convert fp32 -> bf16 (same layout) ----------------
__global__ __launch_bounds__(256) void convert16_k(
    const float* __restrict__ in, ushort* __restrict__ out, int n)
{
    int i = blockIdx.x * 256 + threadIdx.x;
    if (i < n) out[i] = f2b(in[i]);
}

// ---------------- weight prep: out[N][KS] = bf16(in[k0+k][n]), in row-major [*, N] ----------------
__global__ __launch_bounds__(256) void transpose16_k(
    const float* __restrict__ in, ushort* __restrict__ out, int k0, int KS, int N)
{
    int i = blockIdx.x * 256 + threadIdx.x;
    if (i >= KS * N) return;
    int k = i / N, n = i - k * N;
    out[(size_t)n * KS + k] = f2b(in[(size_t)(k0 + k) * N + n]);
}

// ---------------- bf16 MFMA GEMM: C = act(A@B + bias) ----------------
// A fp32 [M,K] (optional row-gather), BT bf16 [N,K], C fp32 or bf16 [M,N].
// 128x128 tile, BK=32, 256 threads (4 waves, each 64x64 = 4x4 MFMA tiles).
__global__ __launch_bounds__(256) void gemm16_k(
    const float* __restrict__ A, const int* __restrict__ a_idx,
    const ushort* __restrict__ BT, const float* __restrict__ bias,
    float* __restrict__ C, ushort* __restrict__ C16,
    int M, int N, int K, int act)
{
    __shared__ ushort As[128 * 40];   // row stride 40 (pad 8) -> 2-way-free banks
    __shared__ ushort Bs[128 * 40];
    const int tid = threadIdx.x;
    const int m0 = blockIdx.x * 128, n0 = blockIdx.y * 128;

    // A staging map: thread covers rows rowbase+i*32 (i<4), float4 slot f4
    const int rowbase = tid >> 3, f4 = tid & 7;
    const float* arow[4];
    #pragma unroll
    for (int i = 0; i < 4; ++i) {
        int r = m0 + rowbase + i * 32;
        if (r < M) {
            int rr = a_idx ? a_idx[r] : r;
            arow[i] = A + (size_t)rr * K;
        } else arow[i] = nullptr;
    }
    // B staging map: rows brow+i*64 (i<2), 16B segment bseg
    const int brow = tid >> 2, bseg = tid & 3;

    const int l = tid & 63, w = tid >> 6;
    const int wm = (w & 1) * 64, wn = (w >> 1) * 64;
    const int cl = l & 15, q = l >> 4;
    const int aoff = (wm + cl) * 40 + q * 8;
    const int boff = (wn + cl) * 40 + q * 8;

    floatx4 acc[4][4];
    #pragma unroll
    for (int mi = 0; mi < 4; ++mi)
        #pragma unroll
        for (int ni = 0; ni < 4; ++ni) acc[mi][ni] = 0.f;

    for (int k0 = 0; k0 < K; k0 += 32) {
        #pragma unroll
        for (int i = 0; i < 4; ++i) {
            float4 v = make_float4(0.f, 0.f, 0.f, 0.f);
            if (arow[i]) v = *(const float4*)(arow[i] + k0 + f4 * 4);
            ushort4 b4;
            b4.x = f2b(v.x); b4.y = f2b(v.y); b4.z = f2b(v.z); b4.w = f2b(v.w);
            *(ushort4*)&As[(rowbase + i * 32) * 40 + f4 * 4] = b4;
        }
        #pragma unroll
        for (int i = 0; i < 2; ++i) {
            int r = brow + i * 64;
            uint4 raw = *(const uint4*)(BT + (size_t)(n0 + r) * K + k0 + bseg * 8);
            *(uint4*)&Bs[r * 40 + bseg * 8] = raw;
        }
        __syncthreads();
        short8 af[4], bf[4];
        #pragma unroll
        for (int mi = 0; mi < 4; ++mi) af[mi] = *(short8*)&As[aoff + mi * 640];
        #pragma unroll
        for (int ni = 0; ni < 4; ++ni) bf[ni] = *(short8*)&Bs[boff + ni * 640];
        #pragma unroll
        for (int mi = 0; mi < 4; ++mi)
            #pragma unroll
            for (int ni = 0; ni < 4; ++ni)
                acc[mi][ni] = __builtin_amdgcn_mfma_f32_16x16x32_bf16(
                    af[mi], bf[ni], acc[mi][ni], 0, 0, 0);
        __syncthreads();
    }

    // epilogue: C/D layout col=lane&15, row=quad*4+reg
    #pragma unroll
    for (int ni = 0; ni < 4; ++ni) {
        int col = n0 + wn + ni * 16 + cl;
        float bv = bias ? bias[col] : 0.f;
        #pragma unroll
        for (int mi = 0; mi < 4; ++mi) {
            int row0 = m0 + wm + mi * 16 + q * 4;
            #pragma unroll
            for (int r = 0; r < 4; ++r) {
                int row = row0 + r;
                if (row >= M) continue;
                float v = acc[mi][ni][r] + bv;
                if (act == ACT_LRELU) v = v > 0.f ? v : 0.01f * v;
                if (C16) C16[(size_t)row * N + col] = f2b(v);
                else     C [(size_t)row * N + col] = v;
            }
        }
    }
}

// ---------------- qdot[b] = query_repr[b] . rank_W[256:512] ----------------
__global__ __launch_bounds__(256) void qdot_k(
    const float* __restrict__ q, const float* __restrict__ rank_W,
    float* __restrict__ qdot)
{
    int b = blockIdx.x * 4 + (threadIdx.x >> 6);
    int l = threadIdx.x & 63;
    float s = 0.f;
    #pragma unroll
    for (int k = 0; k < 4; ++k) {
        int h = l + k * 64;
        s += q[(size_t)b * 256 + h] * rank_W[256 + h];
    }
    #pragma unroll
    for (int off = 32; off; off >>= 1) s += __shfl_xor(s, off, 64);
    if (l == 0) qdot[b] = s;
}

// ---------------- per-edge attention alpha (nodeWs in bf16) ----------------
__global__ __launch_bounds__(256) void alpha_k(
    const ushort* __restrict__ nodeWs16, const float* __restrict__ relWr,
    const float* __restrict__ relWqr, const float* __restrict__ bqr,
    const float* __restrict__ w_alpha, const float* __restrict__ b_alpha_p,
    const int* __restrict__ head_node, const int* __restrict__ edge_rel,
    const int* __restrict__ query_rel, float* __restrict__ alpha_out)
{
    const int tid = threadIdx.x;
    const int e0 = blockIdx.x * 32;
    __shared__ int hn[32], er[32], qr[32];
    if (tid < 32) {
        int e = e0 + tid;
        hn[tid] = head_node[e]; er[tid] = edge_rel[e]; qr[tid] = query_rel[e];
    }
    __syncthreads();
    const int tx = tid & 63, ty = tid >> 6;
    const int c = tx * 4;
    const float4 bq = *(const float4*)(bqr + c);
    const float4 wa = *(const float4*)(w_alpha + c);
    float part[8];
    #pragma unroll
    for (int i2 = 0; i2 < 8; ++i2) {
        int i = ty * 8 + i2;
        ushort4 a16 = *(const ushort4*)(nodeWs16 + (size_t)hn[i] * 256 + c);
        float4 b = *(const float4*)(relWr + (size_t)er[i] * 256 + c);
        float4 d = *(const float4*)(relWqr + (size_t)qr[i] * 256 + c);
        float x0 = fmaxf(b2f(a16.x) + b.x + d.x + bq.x, 0.f);
        float x1 = fmaxf(b2f(a16.y) + b.y + d.y + bq.y, 0.f);
        float x2 = fmaxf(b2f(a16.z) + b.z + d.z + bq.z, 0.f);
        float x3 = fmaxf(b2f(a16.w) + b.w + d.w + bq.w, 0.f);
        part[i2] = x0 * wa.x + x1 * wa.y + x2 * wa.z + x3 * wa.w;
    }
    #pragma unroll
    for (int off = 32; off; off >>= 1)
        #pragma unroll
        for (int i2 = 0; i2 < 8; ++i2)
            part[i2] += __shfl_xor(part[i2], off, 64);
    if (tx == 0) {
        float ba = b_alpha_p[0];
        #pragma unroll
        for (int i2 = 0; i2 < 8; ++i2)
            alpha_out[e0 + ty * 8 + i2] = 1.f / (1.f + __expf(-(part[i2] + ba)));
    }
}

// ---------------- CSR build ----------------
__global__ __launch_bounds__(256) void hist_k(
    const int* __restrict__ tail_node, int* __restrict__ deg, int M)
{
    int e = blockIdx.x * 256 + threadIdx.x;
    if (e < M) atomicAdd(&deg[tail_node[e]], 1);
}
__global__ __launch_bounds__(256) void scan1_k(
    const int* __restrict__ deg, int* __restrict__ partial, int N)
{
    __shared__ int sm[256];
    int i = blockIdx.x * 256 + threadIdx.x;
    int v = (i < N) ? deg[i] : 0;
    sm[threadIdx.x] = v;
    __syncthreads();
    for (int off = 128; off; off >>= 1) {
        if (threadIdx.x < off) sm[threadIdx.x] += sm[threadIdx.x + off];
        __syncthreads();
    }
    if (threadIdx.x == 0) partial[blockIdx.x] = sm[0];
}
__global__ __launch_bounds__(256) void scan2_k(
    int* __restrict__ partial, int nPart, int* __restrict__ offsets, int N, int M)
{
    __shared__ int sm[256];
    int t = threadIdx.x;
    int v = (t < nPart) ? partial[t] : 0;
    sm[t] = v;
    __syncthreads();
    for (int off = 1; off < 256; off <<= 1) {
        int add = (t >= off) ? sm[t - off] : 0;
        __syncthreads();
        sm[t] += add;
        __syncthreads();
    }
    if (t < nPart) partial[t] = sm[t] - v;
    if (t == 0) offsets[N] = M;
}
__global__ __launch_bounds__(256) void scan3_k(
    const int* __restrict__ deg, const int* __restrict__ partial,
    int* __restrict__ offsets, int* __restrict__ cursor, int N)
{
    __shared__ int sm[256];
    int i = blockIdx.x * 256 + threadIdx.x;
    int t = threadIdx.x;
    int v = (i < N) ? deg[i] : 0;
    sm[t] = v;
    __syncthreads();
    for (int off = 1; off < 256; off <<= 1) {
        int add = (t >= off) ? sm[t - off] : 0;
        __syncthreads();
        sm[t] += add;
        __syncthreads();
    }
    if (i < N) {
        int excl = partial[blockIdx.x] + sm[t] - v;
        offsets[i] = excl;
        cursor[i] = excl;
    }
}
__global__ __launch_bounds__(256) void fill_k(
    const int* __restrict__ tail_node, int* __restrict__ cursor,
    int* __restrict__ csr, int M)
{
    int e = blockIdx.x * 256 + threadIdx.x;
    if (e < M) {
        int pos = atomicAdd(&cursor[tail_node[e]], 1);
        csr[pos] = e;
    }
}

// ---------------- segment-sum via CSR gather-reduce ----------------
__global__ __launch_bounds__(256) void agg_csr_k(
    const float* __restrict__ relation_emb, const float* __restrict__ entity_emb,
    const float* __restrict__ alpha, const int* __restrict__ edge_rel,
    const int* __restrict__ tail_ent, const int* __restrict__ offsets,
    const int* __restrict__ csr, float* __restrict__ agg)
{
    int node = blockIdx.x * 4 + (threadIdx.x >> 6);
    int lane = threadIdx.x & 63;
    int beg = offsets[node], end = offsets[node + 1];
    int c = lane * 4;
    float4 acc = make_float4(0.f, 0.f, 0.f, 0.f);
    for (int j = beg; j < end; ++j) {
        int e = csr[j];
        float a = alpha[e];
        const float* src = (c < 128)
            ? (relation_emb + (size_t)edge_rel[e] * 128 + c)
            : (entity_emb + (size_t)tail_ent[e] * 128 + (c - 128));
        float4 v = *(const float4*)src;
        acc.x += v.x * a; acc.y += v.y * a;
        acc.z += v.z * a; acc.w += v.w * a;
    }
    *(float4*)(agg + (size_t)node * 256 + c) = acc;
}

// ---------------- GRU elementwise + LayerNorm ----------------
__global__ __launch_bounds__(256) void gru_ln_k(
    const float* __restrict__ gx, const float* __restrict__ gh,
    const float* __restrict__ h_prev, const float* __restrict__ ln_g,
    const float* __restrict__ ln_b, float* __restrict__ h_new, int n0)
{
    int nl = blockIdx.x * 4 + (threadIdx.x >> 6);
    int lane = threadIdx.x & 63;
    int n = n0 + nl;
    const float* gxr = gx + (size_t)nl * 768;
    const float* ghr = gh + (size_t)nl * 768;
    const float* hpr = h_prev + (size_t)n * 256;
    float hv[4]; float s = 0.f, s2 = 0.f;
    #pragma unroll
    for (int q2 = 0; q2 < 4; ++q2) {
        int h = lane + q2 * 64;
        float xr = gxr[h], xz = gxr[256 + h], xn = gxr[512 + h];
        float hr_ = ghr[h], hz_ = ghr[256 + h], hn_ = ghr[512 + h];
        float hp = hpr[h];
        float r = 1.f / (1.f + __expf(-(xr + hr_)));
        float z = 1.f / (1.f + __expf(-(xz + hz_)));
        float nn = tanhf(xn + r * hn_);
        float v = (1.f - z) * nn + z * hp;
        hv[q2] = v; s += v; s2 += v * v;
    }
    #pragma unroll
    for (int off = 32; off; off >>= 1) {
        s  += __shfl_xor(s, off, 64);
        s2 += __shfl_xor(s2, off, 64);
    }
    float mean = s * (1.f / 256.f);
    float var  = s2 * (1.f / 256.f) - mean * mean;
    float rstd = rsqrtf(var + 1e-5f);
    float* outr = h_new + (size_t)n * 256;
    #pragma unroll
    for (int q2 = 0; q2 < 4; ++q2) {
        int h = lane + q2 * 64;
        outr[h] = (hv[q2] - mean) * rstd * ln_g[h] + ln_b[h];
    }
}

// ---------------- fused score: MFMA te@cand_W1 + gathers + rank dot ----------------
// 64 edges/block. Wave w owns cols w*64..w*64+63; mi covers rows 0..63.
__global__ __launch_bounds__(256) void score_mfma_k(
    const float* __restrict__ ent, const ushort* __restrict__ candW1T,
    const float* __restrict__ relCand, const float* __restrict__ hnewCand,
    const float* __restrict__ rank_W, const float* __restrict__ rank_b_p,
    const float* __restrict__ qdot, const int* __restrict__ tail_ent,
    const int* __restrict__ edge_rel, const int* __restrict__ tail_node,
    const int* __restrict__ batch_idx, float* __restrict__ scores)
{
    __shared__ ushort As[64 * 40];
    __shared__ ushort Bs[256 * 40];
    __shared__ int s_te[64], s_er[64], s_tn[64], s_bi[64];
    __shared__ float s_part[4][64];
    const int tid = threadIdx.x;
    const int e0 = blockIdx.x * 64;
    if (tid < 64) {
        int e = e0 + tid;
        s_te[tid] = tail_ent[e]; s_er[tid] = edge_rel[e];
        s_tn[tid] = tail_node[e]; s_bi[tid] = batch_idx[e];
    }
    __syncthreads();

    const int rowbase = tid >> 3, f4 = tid & 7;           // A: rows rowbase, rowbase+32
    const float* ar0 = ent + (size_t)s_te[rowbase] * 128;
    const float* ar1 = ent + (size_t)s_te[rowbase + 32] * 128;
    const int brow = tid >> 2, bseg = tid & 3;            // B: rows brow+i*64, i<4

    const int l = tid & 63, w = tid >> 6;
    const int cl = l & 15, q = l >> 4;
    const int aoff = cl * 40 + q * 8;
    const int boff = (w * 64 + cl) * 40 + q * 8;

    floatx4 acc[4][4];
    #pragma unroll
    for (int mi = 0; mi < 4; ++mi)
        #pragma unroll
        for (int ni = 0; ni < 4; ++ni) acc[mi][ni] = 0.f;

    for (int k0 = 0; k0 < 128; k0 += 32) {
        {
            float4 v0 = *(const float4*)(ar0 + k0 + f4 * 4);
            float4 v1 = *(const float4*)(ar1 + k0 + f4 * 4);
            ushort4 b0, b1;
            b0.x = f2b(v0.x); b0.y = f2b(v0.y); b0.z = f2b(v0.z); b0.w = f2b(v0.w);
            b1.x = f2b(v1.x); b1.y = f2b(v1.y); b1.z = f2b(v1.z); b1.w = f2b(v1.w);
            *(ushort4*)&As[rowbase * 40 + f4 * 4] = b0;
            *(ushort4*)&As[(rowbase + 32) * 40 + f4 * 4] = b1;
        }
        #pragma unroll
        for (int i = 0; i < 4; ++i) {
            int r = brow + i * 64;
            uint4 raw = *(const uint4*)(candW1T + (size_t)r * 128 + k0 + bseg * 8);
            *(uint4*)&Bs[r * 40 + bseg * 8] = raw;
        }
        __syncthreads();
        short8 af[4], bf[4];
        #pragma unroll
        for (int mi = 0; mi < 4; ++mi) af[mi] = *(short8*)&As[aoff + mi * 640];
        #pragma unroll
        for (int ni = 0; ni < 4; ++ni) bf[ni] = *(short8*)&Bs[boff + ni * 640];
        #pragma unroll
        for (int mi = 0; mi < 4; ++mi)
            #pragma unroll
            for (int ni = 0; ni < 4; ++ni)
                acc[mi][ni] = __builtin_amdgcn_mfma_f32_16x16x32_bf16(
                    af[mi], bf[ni], acc[mi][ni], 0, 0, 0);
        __syncthreads();
    }

    // epilogue: add relCand[er] + hnewCand[tn], lrelu, dot rank_W, reduce
    float rowsum[4][4];
    #pragma unroll
    for (int mi = 0; mi < 4; ++mi)
        #pragma unroll
        for (int r = 0; r < 4; ++r) rowsum[mi][r] = 0.f;

    #pragma unroll
    for (int ni = 0; ni < 4; ++ni) {
        int col = w * 64 + ni * 16 + cl;
        float rw = rank_W[col];
        #pragma unroll
        for (int mi = 0; mi < 4; ++mi) {
            #pragma unroll
            for (int r = 0; r < 4; ++r) {
                int row = mi * 16 + q * 4 + r;
                float v = acc[mi][ni][r]
                        + relCand[(size_t)s_er[row] * 256 + col]
                        + hnewCand[(size_t)s_tn[row] * 256 + col];
                v = v > 0.f ? v : 0.01f * v;
                rowsum[mi][r] += v * rw;
            }
        }
    }
    #pragma unroll
    for (int mask = 1; mask <= 8; mask <<= 1)
        #pragma unroll
        for (int mi = 0; mi < 4; ++mi)
            #pragma unroll
            for (int r = 0; r < 4; ++r)
                rowsum[mi][r] += __shfl_xor(rowsum[mi][r], mask, 64);
    if (cl == 0) {
        #pragma unroll
        for (int mi = 0; mi < 4; ++mi)
            #pragma unroll
            for (int r = 0; r < 4; ++r)
                s_part[w][mi * 16 + q * 4 + r] = rowsum[mi][r];
    }
    __syncthreads();
    if (tid < 64) {
        float s = s_part[0][tid] + s_part[1][tid] + s_part[2][tid] + s_part[3][tid]
                + qdot[s_bi[tid]] + rank_b_p[0];
        scores[e0 + tid] = s;
    }
}

// ---------------------------------------------------------------------------
extern "C" void kernel_launch(void* const* d_in, const int* in_sizes, int n_in,
                              void* d_out, int out_size, void* d_ws, size_t ws_size,
                              hipStream_t stream)
{
    const float* entity_emb   = (const float*)d_in[0];
    const float* relation_emb = (const float*)d_in[1];
    const float* node_hidden  = (const float*)d_in[2];
    const float* query_repr   = (const float*)d_in[3];
    const float* Ws    = (const float*)d_in[4];
    const float* Wr    = (const float*)d_in[5];
    const float* Wqr   = (const float*)d_in[6];
    const float* bqr   = (const float*)d_in[7];
    const float* w_alpha = (const float*)d_in[8];
    const float* b_alpha = (const float*)d_in[9];
    const float* W_ih  = (const float*)d_in[10];
    const float* W_hh  = (const float*)d_in[11];
    const float* b_ih  = (const float*)d_in[12];
    const float* b_hh  = (const float*)d_in[13];
    const float* We2h_W = (const float*)d_in[14];
    const float* We2h_b = (const float*)d_in[15];
    const float* cand_W = (const float*)d_in[16];
    const float* cand_b = (const float*)d_in[17];
    const float* rank_W = (const float*)d_in[18];
    const float* rank_b = (const float*)d_in[19];
    const float* ln_g  = (const float*)d_in[20];
    const float* ln_b  = (const float*)d_in[21];
    const int* head_node = (const int*)d_in[22];
    const int* edge_rel  = (const int*)d_in[23];
    const int* tail_ent  = (const int*)d_in[24];
    const int* tail_node = (const int*)d_in[25];
    const int* query_rel = (const int*)d_in[26];
    const int* batch_idx = (const int*)d_in[27];
    const int* tail_node_ent = (const int*)d_in[28];
    float* out = (float*)d_out;
    (void)in_sizes; (void)n_in; (void)out_size; (void)ws_size;

    const int M = 200000, NNEW = 50000, NNODES = 100000, NREL = 500;
    const int NCHUNK = 4, NC = NNEW / NCHUNK;   // 12500
    const int NPART = (NNEW + 255) / 256;

    // ---- workspace layout (float units) ----
    float* w = (float*)d_ws;
    float* relWr    = w; w += NREL * 256;
    float* relWqr   = w; w += NREL * 256;
    float* relCand  = w; w += NREL * 256;
    float* qdot     = w; w += 256;
    float* alpha    = w; w += M;
    float* agg      = w; w += (size_t)NNEW * 256;
    float* h_prev   = w; w += (size_t)NNEW * 256;
    float* h_new    = w; w += (size_t)NNEW * 256;
    float* hnewCand = w; w += (size_t)NNEW * 256;
    int* deg     = (int*)w; w += NNEW;
    int* offsets = (int*)w; w += NNEW + 1;
    int* cursor  = (int*)w; w += NNEW;
    int* partial = (int*)w; w += 256;
    int* csr     = (int*)w; w += M;
    // bf16 weights
    ushort* W_ih16    = (ushort*)w; w += (768 * 256) / 2;
    ushort* W_hh16    = (ushort*)w; w += (768 * 256) / 2;
    ushort* WsT16     = (ushort*)w; w += (256 * 256) / 2;
    ushort* We2hT16   = (ushort*)w; w += (256 * 128) / 2;
    ushort* candW1T16 = (ushort*)w; w += (256 * 128) / 2;
    ushort* candW3T16 = (ushort*)w; w += (256 * 256) / 2;
    // BIG region: nodeWs16 (bf16, phases 2-4) then gx|gh chunks (fp32, phase 7)
    float* big = w;                                  // 76.8 MB
    ushort* nodeWs16 = (ushort*)big;                 // 100000*256 bf16 = 51.2 MB
    float* gx_buf = big;                             // 12500*768 fp32
    float* gh_buf = big + (size_t)NC * 768;

    // (0) CSR build
    hipMemsetAsync(deg, 0, NNEW * sizeof(int), stream);
    hist_k<<<(M + 255) / 256, 256, 0, stream>>>(tail_node, deg, M);
    scan1_k<<<NPART, 256, 0, stream>>>(deg, partial, NNEW);
    scan2_k<<<1, 256, 0, stream>>>(partial, NPART, offsets, NNEW, M);
    scan3_k<<<NPART, 256, 0, stream>>>(deg, partial, offsets, cursor, NNEW);
    fill_k<<<(M + 255) / 256, 256, 0, stream>>>(tail_node, cursor, csr, M);

    // (1) weight prep + relation tables + qdot
    convert16_k<<<768, 256, 0, stream>>>(W_ih, W_ih16, 768 * 256);
    convert16_k<<<768, 256, 0, stream>>>(W_hh, W_hh16, 768 * 256);
    transpose16_k<<<256, 256, 0, stream>>>(Ws, WsT16, 0, 256, 256);
    transpose16_k<<<128, 256, 0, stream>>>(We2h_W, We2hT16, 0, 128, 256);
    transpose16_k<<<128, 256, 0, stream>>>(cand_W, candW1T16, 0, 128, 256);
    transpose16_k<<<256, 256, 0, stream>>>(cand_W, candW3T16, 256, 256, 256);
    gemm_k<<<dim3(8, 4), 256, 0, stream>>>(relation_emb, Wr,  nullptr, relWr,  NREL, 256, 128, nullptr, ACT_NONE);
    gemm_k<<<dim3(8, 4), 256, 0, stream>>>(relation_emb, Wqr, nullptr, relWqr, NREL, 256, 128, nullptr, ACT_NONE);
    gemm_k<<<dim3(8, 4), 256, 0, stream>>>(relation_emb, cand_W + 128 * 256, nullptr, relCand, NREL, 256, 128, nullptr, ACT_NONE);
    qdot_k<<<64, 256, 0, stream>>>(query_repr, rank_W, qdot);

    // (2) nodeWs16 = bf16(node_hidden @ Ws)
    gemm16_k<<<dim3((NNODES + 127) / 128, 2), 256, 0, stream>>>(
        node_hidden, nullptr, WsT16, nullptr, nullptr, nodeWs16, NNODES, 256, 256, ACT_NONE);

    // (3) alpha
    alpha_k<<<M / 32, 256, 0, stream>>>(nodeWs16, relWr, relWqr, bqr, w_alpha, b_alpha,
                                        head_node, edge_rel, query_rel, alpha);

    // (4) segment sum via CSR
    agg_csr_k<<<NNEW / 4, 256, 0, stream>>>(relation_emb, entity_emb, alpha,
                                            edge_rel, tail_ent, offsets, csr, agg);

    // (5) h_prev = lrelu(entity_emb[tail_node_ent] @ We2h_W + We2h_b)
    gemm16_k<<<dim3((NNEW + 127) / 128, 2), 256, 0, stream>>>(
        entity_emb, tail_node_ent, We2hT16, We2h_b, h_prev, nullptr, NNEW, 256, 128, ACT_LRELU);

    // (6,7) GRU chunks (gx/gh alias the nodeWs16 region — alpha already done)
    for (int ch = 0; ch < NCHUNK; ++ch) {
        int n0 = ch * NC;
        gemm16_k<<<dim3((NC + 127) / 128, 6), 256, 0, stream>>>(
            agg + (size_t)n0 * 256, nullptr, W_ih16, b_ih, gx_buf, nullptr, NC, 768, 256, ACT_NONE);
        gemm16_k<<<dim3((NC + 127) / 128, 6), 256, 0, stream>>>(
            h_prev + (size_t)n0 * 256, nullptr, W_hh16, b_hh, gh_buf, nullptr, NC, 768, 256, ACT_NONE);
        gru_ln_k<<<NC / 4, 256, 0, stream>>>(gx_buf, gh_buf, h_prev, ln_g, ln_b, h_new, n0);
    }

    // (8) hnewCand = h_new @ cand_W[256:512] + cand_b
    gemm16_k<<<dim3((NNEW + 127) / 128, 2), 256, 0, stream>>>(
        h_new, nullptr, candW3T16, cand_b, hnewCand, nullptr, NNEW, 256, 256, ACT_NONE);

    // (9) fused score
    score_mfma_k<<<M / 64, 256, 0, stream>>>(entity_emb, candW1T16, relCand, hnewCand,
                                             rank_W, rank_b, qdot, tail_ent, edge_rel,
                                             tail_node, batch_idx, out);
}